// Round 12
// baseline (369.116 us; speedup 1.0000x reference)
//
#include <hip/hip_runtime.h>
#include <hip/hip_fp16.h>
#include <math.h>

#define IN_F 64
#define OUT_F 32
#define NEG_SLOPE 0.2f

#define BK_SHIFT 6
#define BK 64            // nodes per bucket
#define NBMAX 2048       // max buckets (N <= 131072)
#define NPART 2048       // partition-role blocks (fused into k_projpart)
#define PSTAGE 3         // k_pg register staging (512 thr x 3 = 1536 >= ~1024+6sigma)
#define CAPSHIFT 11
#define CAP 2048         // fixed recs capacity per bucket (mean 1024, sd 32)
#define COLCAP 2048      // LDS col capacity per bucket

typedef _Float16 half8_t __attribute__((ext_vector_type(8)));
typedef float float4_t __attribute__((ext_vector_type(4)));
typedef int int4_t __attribute__((ext_vector_type(4)));

// SESSION FINDINGS:
//  - gfx950 LDS atomics ~4.2 cy per LANE-op, unpipelined RMW. Budget 1-2/edge.
//  - k_pg at its DS+VMEM overlap floor (~44us).
//  - r11: two-pass LDS bpart at NBLKA=256 = 1 block/CU -> VALUBusy 1.4%,
//    occupancy 16.6%, 44.8us: latency-bound. r12: single-pass direct global
//    atomicAdd reservation (no LDS, no chains), fused into the projection
//    kernel so the atomic/memory-bound partition overlaps the VALU-bound proj.

__device__ __forceinline__ float leaky(float v) {
    return (v > 0.0f) ? v : NEG_SLOPE * v;
}

// Inclusive block scan, 512 threads. wsum: >=8-int LDS scratch.
__device__ __forceinline__ int incScan512(int v, int tid, int* wsum) {
    const int lane = tid & 63, wid = tid >> 6;
    #pragma unroll
    for (int m = 1; m < 64; m <<= 1) {
        int u = __shfl_up(v, m);
        if (lane >= m) v += u;
    }
    if (lane == 63) wsum[wid] = v;
    __syncthreads();
    int add = 0;
    for (int k = 0; k < wid; ++k) add += wsum[k];
    __syncthreads();
    return v + add;
}

// Fused projection + partition.
// Blocks [0, PB): MFMA projection (16 nodes/wave, 64/block, no LDS).
// Blocks [PB, PB+NPART): direct-reservation partition: per edge ONE global
//   atomicAdd(cursor[b],1) (cursor pre-memset to 0) + one packed-record store
//   into the bucket's fixed-CAP region. No LDS, no dependent chains.
// Block PB+NPART: gather sentinel init (h2 row N = 0, asrc[N] = -1e30).
__global__ __launch_bounds__(256) void k_projpart(
        const float* __restrict__ x, const float* __restrict__ W,
        const float* __restrict__ att_src, const float* __restrict__ att_dst,
        __half2* __restrict__ h2, float* __restrict__ asrc, float* __restrict__ adst,
        const int* __restrict__ src, const int* __restrict__ dst,
        int* __restrict__ cursor, int* __restrict__ recs,
        int N, int E, int PB) {
    const int tid = threadIdx.x;

    if (blockIdx.x >= PB + NPART) {
        // ---- sentinel init role ----
        if (tid < 16) h2[(size_t)N * 16 + tid] = __floats2half2_rn(0.0f, 0.0f);
        if (tid == 16) asrc[N] = -1e30f;
        return;
    }
    if (blockIdx.x >= PB) {
        // ---- partition role ----
        const int blk = blockIdx.x - PB;
        for (int e = blk * 256 + tid; e < E; e += NPART * 256) {
            const int s = src[e];
            const int d = dst[e];
            const int b = d >> BK_SHIFT;
            const int idx = atomicAdd(&cursor[b], 1);
            if (idx < CAP)
                recs[((size_t)b << CAPSHIFT) + idx] = ((d & (BK - 1)) << 17) | s;
        }
        return;
    }

    // ---- MFMA projection role ----
    const int wv   = tid >> 6;               // wave 0..3
    const int lane = tid & 63;
    const int m    = lane & 15;              // node-in-16 (A) / channel-in-group (B, C/D)
    const int quad = lane >> 4;              // 0..3
    const int node0 = (blockIdx.x * 4 + wv) * 16;
    if (node0 >= N) return;

    const int kb = quad * 8;
    // B fragments (W is 64x32, row-major W[k*32+c]); built once, L2-hot.
    half8_t b00, b01, b10, b11;
    #pragma unroll
    for (int j = 0; j < 8; ++j) {
        b00[j] = (_Float16)W[(kb + j) * OUT_F + m];
        b01[j] = (_Float16)W[(32 + kb + j) * OUT_F + m];
        b10[j] = (_Float16)W[(kb + j) * OUT_F + 16 + m];
        b11[j] = (_Float16)W[(32 + kb + j) * OUT_F + 16 + m];
    }
    // A fragments: x row (clamped in the tail block), 2x float4 per K-chunk.
    const int row = min(node0 + m, N - 1);
    const float* xr = x + (size_t)row * IN_F + kb;
    float4_t xa = *(const float4_t*)(xr);
    float4_t xb = *(const float4_t*)(xr + 4);
    float4_t xc = *(const float4_t*)(xr + 32);
    float4_t xd = *(const float4_t*)(xr + 36);
    half8_t a0, a1;
    #pragma unroll
    for (int j = 0; j < 4; ++j) {
        a0[j] = (_Float16)xa[j]; a0[4 + j] = (_Float16)xb[j];
        a1[j] = (_Float16)xc[j]; a1[4 + j] = (_Float16)xd[j];
    }
    float4_t acc0 = {0.f, 0.f, 0.f, 0.f};
    float4_t acc1 = {0.f, 0.f, 0.f, 0.f};
    acc0 = __builtin_amdgcn_mfma_f32_16x16x32_f16(a0, b00, acc0, 0, 0, 0);
    acc0 = __builtin_amdgcn_mfma_f32_16x16x32_f16(a1, b01, acc0, 0, 0, 0);
    acc1 = __builtin_amdgcn_mfma_f32_16x16x32_f16(a0, b10, acc1, 0, 0, 0);
    acc1 = __builtin_amdgcn_mfma_f32_16x16x32_f16(a1, b11, acc1, 0, 0, 0);

    // Epilogue: h2 (fp16 pairs) + asrc/adst per node.
    const float aS0 = att_src[m], aS1 = att_src[16 + m];
    const float aD0 = att_dst[m], aD1 = att_dst[16 + m];
    #pragma unroll
    for (int r = 0; r < 4; ++r) {
        const int node = node0 + quad * 4 + r;
        float h0 = acc0[r], h1 = acc1[r];
        float h0p = __shfl_xor(h0, 1);
        float h1p = __shfl_xor(h1, 1);
        if (node < N && (m & 1) == 0) {
            __half2 hv;
            hv.x = __float2half_rn(h0); hv.y = __float2half_rn(h0p);
            h2[(size_t)node * 16 + (m >> 1)] = hv;
            __half2 hw;
            hw.x = __float2half_rn(h1); hw.y = __float2half_rn(h1p);
            h2[(size_t)node * 16 + 8 + (m >> 1)] = hw;
        }
        float vs = h0 * aS0 + h1 * aS1;
        float vd = h0 * aD0 + h1 * aD1;
        #pragma unroll
        for (int mm = 1; mm < 16; mm <<= 1) {
            vs += __shfl_xor(vs, mm);
            vd += __shfl_xor(vd, mm);
        }
        if (node < N && m == 0) {
            asrc[node] = vs;
            adst[node] = vd;
        }
    }
}

// Fused place+gather: one block per bucket (64 nodes, 512 threads = 8 waves).
// cb0 = b*CAP; count = cursor[b] (cursor is now a pure count). Phase 1
// (place): fine histogram of recs; padded (x4) scan; place col into
// sentinel-prefilled LDS. Phase 2 (gather): wave w handles nodes w*8..w*8+7;
// 4x16-lane groups read chunk lists from LDS and gather h2/asrc from global.
__global__ __launch_bounds__(512) void k_pg(const int* __restrict__ recs,
                                            const int* __restrict__ cursor,
                                            const float* __restrict__ asrc,
                                            const float* __restrict__ adst,
                                            const __half2* __restrict__ h2,
                                            const float* __restrict__ bias,
                                            float* __restrict__ out,
                                            int NB, int E, int N) {
    __shared__ __align__(16) int colsh[COLCAP];
    __shared__ int fineCnt[BK];
    __shared__ int cur[BK];
    __shared__ int loff[BK];
    __shared__ int lpad[BK];
    __shared__ int wsum[8];
    const int b = blockIdx.x, tid = threadIdx.x;
    const int node0 = b << BK_SHIFT;

    const size_t cb0 = (size_t)b << CAPSHIFT;
    const int count = min(cursor[b], CAP);

    // ---- init: sentinel prefill + zero counts ----
    for (int i = tid; i < COLCAP; i += 512) colsh[i] = N;
    if (tid < BK) fineCnt[tid] = 0;
    __syncthreads();

    // ---- fine histogram (register-staged) ----
    int myrec[PSTAGE];
    #pragma unroll
    for (int k = 0; k < PSTAGE; ++k) {
        int i = tid + k * 512;
        if (i < count) {
            int v = recs[cb0 + i];
            myrec[k] = v;
            atomicAdd(&fineCnt[v >> 17], 1);
        }
    }
    for (int i = tid + PSTAGE * 512; i < count; i += 512)   // statistically never
        atomicAdd(&fineCnt[recs[cb0 + i] >> 17], 1);
    __syncthreads();

    // ---- padded (x4) scan of per-node counts ----
    const int v0 = (tid < BK) ? fineCnt[tid] : 0;
    const int pv = (v0 + 3) & ~3;
    const int vin = (tid < BK) ? pv : 0;
    const int pinc = incScan512(vin, tid, wsum);
    const int pexcl = pinc - vin;
    if (tid < BK) {
        loff[tid] = pexcl;       // multiple of 4 -> 16B-aligned chunks
        lpad[tid] = pv;
        cur[tid]  = pexcl;
    }
    __syncthreads();

    // ---- place into LDS col ----
    #pragma unroll
    for (int k = 0; k < PSTAGE; ++k) {
        int i = tid + k * 512;
        if (i < count) {
            int r = myrec[k];
            int p = atomicAdd(&cur[r >> 17], 1);
            colsh[p] = r & 0x1FFFF;
        }
    }
    for (int i = tid + PSTAGE * 512; i < count; i += 512) {
        int r = recs[cb0 + i];
        int p = atomicAdd(&cur[r >> 17], 1);
        colsh[p] = r & 0x1FFFF;
    }
    __syncthreads();

    // ---- gather: wave w -> nodes node0 + w*8 .. +7 ----
    const int wid  = tid >> 6;
    const int lane = tid & 63;
    const int g    = lane >> 4;      // edge group 0..3
    const int c2   = lane & 15;      // half2 channel pair
    for (int i = 0; i < 8; ++i) {
        const int dloc = wid * 8 + i;
        const int n = node0 + dloc;
        if (n >= N) break;           // only the tail bucket; uniform per wave
        const float adst_n = adst[n];
        float l = 0.0f, accx = 0.0f, accy = 0.0f;
        if (g == 0) {                // self loop
            float p = __expf(leaky(asrc[n] + adst_n));
            float2 hv = __half22float2(h2[(size_t)n * 16 + c2]);
            l = p; accx = p * hv.x; accy = p * hv.y;
        }
        const int base = loff[dloc];
        const int nch  = lpad[dloc] >> 2;    // 4-edge chunks
        for (int c = g; c < nch; c += 4) {   // clamp-free (sentinel-padded x4)
            const int4_t cc = *(const int4_t*)(&colsh[base + c * 4]);
            const int s0 = cc[0], s1 = cc[1], s2 = cc[2], s3 = cc[3];
            float a0 = asrc[s0], a1 = asrc[s1], a2 = asrc[s2], a3 = asrc[s3];
            float2 h0 = __half22float2(h2[(size_t)s0 * 16 + c2]);
            float2 h1 = __half22float2(h2[(size_t)s1 * 16 + c2]);
            float2 hv2 = __half22float2(h2[(size_t)s2 * 16 + c2]);
            float2 h3 = __half22float2(h2[(size_t)s3 * 16 + c2]);
            float p0 = __expf(leaky(a0 + adst_n));
            float p1 = __expf(leaky(a1 + adst_n));
            float p2 = __expf(leaky(a2 + adst_n));
            float p3 = __expf(leaky(a3 + adst_n));
            l += (p0 + p1) + (p2 + p3);
            accx += p0 * h0.x + p1 * h1.x + p2 * hv2.x + p3 * h3.x;
            accy += p0 * h0.y + p1 * h1.y + p2 * hv2.y + p3 * h3.y;
        }
        l    += __shfl_xor(l, 16);    l    += __shfl_xor(l, 32);
        accx += __shfl_xor(accx, 16); accx += __shfl_xor(accx, 32);
        accy += __shfl_xor(accy, 16); accy += __shfl_xor(accy, 32);
        if (g == 0) {
            float inv = 1.0f / l;
            float2 bb = ((const float2*)bias)[c2];
            float2 o;
            o.x = fmaxf(accx * inv + bb.x, 0.0f);
            o.y = fmaxf(accy * inv + bb.y, 0.0f);
            ((float2*)out)[(size_t)n * 16 + c2] = o;
        }
    }
}

extern "C" void kernel_launch(void* const* d_in, const int* in_sizes, int n_in,
                              void* d_out, int out_size, void* d_ws, size_t ws_size,
                              hipStream_t stream) {
    const float* x        = (const float*)d_in[0];
    const int*   eidx     = (const int*)d_in[1];   // [2, E] flat int32
    const float* W        = (const float*)d_in[2];
    const float* att_src  = (const float*)d_in[3];
    const float* att_dst  = (const float*)d_in[4];
    const float* bias     = (const float*)d_in[5];
    float* out = (float*)d_out;

    const int N = in_sizes[0] / IN_F;
    const int E = in_sizes[1] / 2;
    const int* src = eidx;
    const int* dst = eidx + E;

    const int NB  = (N + BK - 1) >> BK_SHIFT;    // 1563 buckets

    // Workspace (4 B elems, ~21 MB)
    int* u = (int*)d_ws;
    size_t o = 0;
    __half2* h2     = (__half2*)(u + o); o += (size_t)(N + 1) * 16;   // +sentinel row
    float*   asrc   = (float*)(u + o);   o += N + 1;                  // +sentinel
    float*   adst   = (float*)(u + o);   o += N;
    int*     cursor = u + o;             o += NBMAX;
    int*     recs   = u + o;             o += (size_t)NBMAX * CAP;    // fixed-CAP regions

    const int PB = (N + 63) / 64;                // MFMA proj blocks (64 nodes/block)

    hipMemsetAsync(cursor, 0, NBMAX * sizeof(int), stream);
    k_projpart<<<PB + NPART + 1, 256, 0, stream>>>(x, W, att_src, att_dst,
                                                   h2, asrc, adst, src, dst,
                                                   cursor, recs, N, E, PB);
    k_pg<<<NB, 512, 0, stream>>>(recs, cursor, asrc, adst, h2, bias, out, NB, E, N);
}

// Round 13
// 215.315 us; speedup vs baseline: 1.7143x; 1.7143x over previous
//
#include <hip/hip_runtime.h>
#include <hip/hip_fp16.h>
#include <math.h>

#define IN_F 64
#define OUT_F 32
#define NEG_SLOPE 0.2f

#define BK_SHIFT 6
#define BK 64            // nodes per bucket
#define NBMAX 2048       // max buckets (N <= 131072)
#define NPART 2048       // partition-role blocks (fused into k_projpart)
#define NSUB 16          // sub-cursors per bucket (breaks same-address chains)
#define SUBSHIFT 7
#define SUBCAP 128       // slots per sub-region (Poisson mean 64, +8 sigma)
#define REGSHIFT 11      // bucket region = NSUB*SUBCAP = 2048 ints
#define PSTAGE 4         // 512 thr x 4 = 2048 = max records per bucket region
#define COLCAP 2304      // LDS col capacity (2048 + pad slack 192, rounded up)

typedef _Float16 half8_t __attribute__((ext_vector_type(8)));
typedef float float4_t __attribute__((ext_vector_type(4)));
typedef int int4_t __attribute__((ext_vector_type(4)));

// SESSION FINDINGS:
//  - gfx950 LDS atomics ~4.2 cy per LANE-op (per-CU DS throughput). 1-2/edge max.
//  - gfx950 global SAME-ADDRESS atomics serialize ~200-240ns/op at the
//    coherence point (r12: 1024-deep chains = 245us). Chain depth budget <=64.
//  - k_pg at its DS+VMEM overlap floor (~44us).
//  - r13: direct reservation kept, but 16 sub-cursors/bucket (j=(e>>8)&15)
//    cut chain depth 1024->64; k_pg rebuilds order via 16-entry prefix +
//    4-step binary search.

__device__ __forceinline__ float leaky(float v) {
    return (v > 0.0f) ? v : NEG_SLOPE * v;
}

// Inclusive block scan, 512 threads. wsum: >=8-int LDS scratch.
__device__ __forceinline__ int incScan512(int v, int tid, int* wsum) {
    const int lane = tid & 63, wid = tid >> 6;
    #pragma unroll
    for (int m = 1; m < 64; m <<= 1) {
        int u = __shfl_up(v, m);
        if (lane >= m) v += u;
    }
    if (lane == 63) wsum[wid] = v;
    __syncthreads();
    int add = 0;
    for (int k = 0; k < wid; ++k) add += wsum[k];
    __syncthreads();
    return v + add;
}

// Fused projection + partition.
// Blocks [0, PB): MFMA projection (16 nodes/wave, 64/block, no LDS).
// Blocks [PB, PB+NPART): sub-cursor direct reservation: per edge ONE global
//   atomicAdd(cursor[b*NSUB+j],1), j=(e>>8)&15, + packed-record store into the
//   (b,j) sub-region. Chains <=~64 deep.
// Block PB+NPART: gather sentinel init (h2 row N = 0, asrc[N] = -1e30).
__global__ __launch_bounds__(256) void k_projpart(
        const float* __restrict__ x, const float* __restrict__ W,
        const float* __restrict__ att_src, const float* __restrict__ att_dst,
        __half2* __restrict__ h2, float* __restrict__ asrc, float* __restrict__ adst,
        const int* __restrict__ src, const int* __restrict__ dst,
        int* __restrict__ cursor, int* __restrict__ recs,
        int N, int E, int PB) {
    const int tid = threadIdx.x;

    if (blockIdx.x >= PB + NPART) {
        // ---- sentinel init role ----
        if (tid < 16) h2[(size_t)N * 16 + tid] = __floats2half2_rn(0.0f, 0.0f);
        if (tid == 16) asrc[N] = -1e30f;
        return;
    }
    if (blockIdx.x >= PB) {
        // ---- partition role ----
        const int blk = blockIdx.x - PB;
        for (int e = blk * 256 + tid; e < E; e += NPART * 256) {
            const int s = src[e];
            const int d = dst[e];
            const int b = d >> BK_SHIFT;
            const int j = (e >> 8) & (NSUB - 1);
            const int idx = atomicAdd(&cursor[b * NSUB + j], 1);
            if (idx < SUBCAP)
                recs[((size_t)b << REGSHIFT) + (j << SUBSHIFT) + idx] =
                    ((d & (BK - 1)) << 17) | s;
        }
        return;
    }

    // ---- MFMA projection role ----
    const int wv   = tid >> 6;               // wave 0..3
    const int lane = tid & 63;
    const int m    = lane & 15;              // node-in-16 (A) / channel-in-group (B, C/D)
    const int quad = lane >> 4;              // 0..3
    const int node0 = (blockIdx.x * 4 + wv) * 16;
    if (node0 >= N) return;

    const int kb = quad * 8;
    // B fragments (W is 64x32, row-major W[k*32+c]); built once, L2-hot.
    half8_t b00, b01, b10, b11;
    #pragma unroll
    for (int j = 0; j < 8; ++j) {
        b00[j] = (_Float16)W[(kb + j) * OUT_F + m];
        b01[j] = (_Float16)W[(32 + kb + j) * OUT_F + m];
        b10[j] = (_Float16)W[(kb + j) * OUT_F + 16 + m];
        b11[j] = (_Float16)W[(32 + kb + j) * OUT_F + 16 + m];
    }
    // A fragments: x row (clamped in the tail block), 2x float4 per K-chunk.
    const int row = min(node0 + m, N - 1);
    const float* xr = x + (size_t)row * IN_F + kb;
    float4_t xa = *(const float4_t*)(xr);
    float4_t xb = *(const float4_t*)(xr + 4);
    float4_t xc = *(const float4_t*)(xr + 32);
    float4_t xd = *(const float4_t*)(xr + 36);
    half8_t a0, a1;
    #pragma unroll
    for (int j = 0; j < 4; ++j) {
        a0[j] = (_Float16)xa[j]; a0[4 + j] = (_Float16)xb[j];
        a1[j] = (_Float16)xc[j]; a1[4 + j] = (_Float16)xd[j];
    }
    float4_t acc0 = {0.f, 0.f, 0.f, 0.f};
    float4_t acc1 = {0.f, 0.f, 0.f, 0.f};
    acc0 = __builtin_amdgcn_mfma_f32_16x16x32_f16(a0, b00, acc0, 0, 0, 0);
    acc0 = __builtin_amdgcn_mfma_f32_16x16x32_f16(a1, b01, acc0, 0, 0, 0);
    acc1 = __builtin_amdgcn_mfma_f32_16x16x32_f16(a0, b10, acc1, 0, 0, 0);
    acc1 = __builtin_amdgcn_mfma_f32_16x16x32_f16(a1, b11, acc1, 0, 0, 0);

    // Epilogue: h2 (fp16 pairs) + asrc/adst per node.
    const float aS0 = att_src[m], aS1 = att_src[16 + m];
    const float aD0 = att_dst[m], aD1 = att_dst[16 + m];
    #pragma unroll
    for (int r = 0; r < 4; ++r) {
        const int node = node0 + quad * 4 + r;
        float h0 = acc0[r], h1 = acc1[r];
        float h0p = __shfl_xor(h0, 1);
        float h1p = __shfl_xor(h1, 1);
        if (node < N && (m & 1) == 0) {
            __half2 hv;
            hv.x = __float2half_rn(h0); hv.y = __float2half_rn(h0p);
            h2[(size_t)node * 16 + (m >> 1)] = hv;
            __half2 hw;
            hw.x = __float2half_rn(h1); hw.y = __float2half_rn(h1p);
            h2[(size_t)node * 16 + 8 + (m >> 1)] = hw;
        }
        float vs = h0 * aS0 + h1 * aS1;
        float vd = h0 * aD0 + h1 * aD1;
        #pragma unroll
        for (int mm = 1; mm < 16; mm <<= 1) {
            vs += __shfl_xor(vs, mm);
            vd += __shfl_xor(vd, mm);
        }
        if (node < N && m == 0) {
            asrc[node] = vs;
            adst[node] = vd;
        }
    }
}

// Fused place+gather: one block per bucket (64 nodes, 512 threads = 8 waves).
// Records live in 16 sub-regions of 128 slots; valid prefix per sub-region =
// min(cursor[b*16+j], 128). A 16-entry prefix (pre[]) + 4-step binary search
// maps flat index i -> (j, off). Phase 1 (place): fine histogram; padded (x4)
// scan; place col into sentinel-prefilled LDS. Phase 2 (gather): wave w
// handles nodes w*8..w*8+7; 4x16-lane groups gather h2/asrc from global.
__global__ __launch_bounds__(512) void k_pg(const int* __restrict__ recs,
                                            const int* __restrict__ cursor,
                                            const float* __restrict__ asrc,
                                            const float* __restrict__ adst,
                                            const __half2* __restrict__ h2,
                                            const float* __restrict__ bias,
                                            float* __restrict__ out,
                                            int NB, int E, int N) {
    __shared__ __align__(16) int colsh[COLCAP];
    __shared__ int fineCnt[BK];
    __shared__ int cur[BK];
    __shared__ int loff[BK];
    __shared__ int lpad[BK];
    __shared__ int pre[NSUB + 1];
    __shared__ int wsum[8];
    const int b = blockIdx.x, tid = threadIdx.x;
    const int node0 = b << BK_SHIFT;
    const size_t rb = (size_t)b << REGSHIFT;

    // ---- init: sub-count prefix + sentinel prefill + zero counts ----
    if (tid == 0) {
        int a = 0;
        #pragma unroll
        for (int j = 0; j < NSUB; ++j) {
            pre[j] = a;
            a += min(cursor[b * NSUB + j], SUBCAP);
        }
        pre[NSUB] = a;
    }
    for (int i = tid; i < COLCAP; i += 512) colsh[i] = N;
    if (tid < BK) fineCnt[tid] = 0;
    __syncthreads();
    const int total = pre[NSUB];

    // ---- fine histogram (register-staged; flat idx -> sub-region via search) ----
    int myrec[PSTAGE];
    #pragma unroll
    for (int k = 0; k < PSTAGE; ++k) {
        int i = tid + k * 512;
        if (i < total) {
            int lo = 0;
            #pragma unroll
            for (int st = 8; st >= 1; st >>= 1)
                if (pre[lo + st] <= i) lo += st;
            int v = recs[rb + (lo << SUBSHIFT) + (i - pre[lo])];
            myrec[k] = v;
            atomicAdd(&fineCnt[v >> 17], 1);
        }
    }
    __syncthreads();

    // ---- padded (x4) scan of per-node counts ----
    const int v0 = (tid < BK) ? fineCnt[tid] : 0;
    const int pv = (v0 + 3) & ~3;
    const int vin = (tid < BK) ? pv : 0;
    const int pinc = incScan512(vin, tid, wsum);
    const int pexcl = pinc - vin;
    if (tid < BK) {
        loff[tid] = pexcl;       // multiple of 4 -> 16B-aligned chunks
        lpad[tid] = pv;
        cur[tid]  = pexcl;
    }
    __syncthreads();

    // ---- place into LDS col ----
    #pragma unroll
    for (int k = 0; k < PSTAGE; ++k) {
        int i = tid + k * 512;
        if (i < total) {
            int r = myrec[k];
            int p = atomicAdd(&cur[r >> 17], 1);
            colsh[p] = r & 0x1FFFF;
        }
    }
    __syncthreads();

    // ---- gather: wave w -> nodes node0 + w*8 .. +7 ----
    const int wid  = tid >> 6;
    const int lane = tid & 63;
    const int g    = lane >> 4;      // edge group 0..3
    const int c2   = lane & 15;      // half2 channel pair
    for (int i = 0; i < 8; ++i) {
        const int dloc = wid * 8 + i;
        const int n = node0 + dloc;
        if (n >= N) break;           // only the tail bucket; uniform per wave
        const float adst_n = adst[n];
        float l = 0.0f, accx = 0.0f, accy = 0.0f;
        if (g == 0) {                // self loop
            float p = __expf(leaky(asrc[n] + adst_n));
            float2 hv = __half22float2(h2[(size_t)n * 16 + c2]);
            l = p; accx = p * hv.x; accy = p * hv.y;
        }
        const int base = loff[dloc];
        const int nch  = lpad[dloc] >> 2;    // 4-edge chunks
        for (int c = g; c < nch; c += 4) {   // clamp-free (sentinel-padded x4)
            const int4_t cc = *(const int4_t*)(&colsh[base + c * 4]);
            const int s0 = cc[0], s1 = cc[1], s2 = cc[2], s3 = cc[3];
            float a0 = asrc[s0], a1 = asrc[s1], a2 = asrc[s2], a3 = asrc[s3];
            float2 h0 = __half22float2(h2[(size_t)s0 * 16 + c2]);
            float2 h1 = __half22float2(h2[(size_t)s1 * 16 + c2]);
            float2 hv2 = __half22float2(h2[(size_t)s2 * 16 + c2]);
            float2 h3 = __half22float2(h2[(size_t)s3 * 16 + c2]);
            float p0 = __expf(leaky(a0 + adst_n));
            float p1 = __expf(leaky(a1 + adst_n));
            float p2 = __expf(leaky(a2 + adst_n));
            float p3 = __expf(leaky(a3 + adst_n));
            l += (p0 + p1) + (p2 + p3);
            accx += p0 * h0.x + p1 * h1.x + p2 * hv2.x + p3 * h3.x;
            accy += p0 * h0.y + p1 * h1.y + p2 * hv2.y + p3 * h3.y;
        }
        l    += __shfl_xor(l, 16);    l    += __shfl_xor(l, 32);
        accx += __shfl_xor(accx, 16); accx += __shfl_xor(accx, 32);
        accy += __shfl_xor(accy, 16); accy += __shfl_xor(accy, 32);
        if (g == 0) {
            float inv = 1.0f / l;
            float2 bb = ((const float2*)bias)[c2];
            float2 o;
            o.x = fmaxf(accx * inv + bb.x, 0.0f);
            o.y = fmaxf(accy * inv + bb.y, 0.0f);
            ((float2*)out)[(size_t)n * 16 + c2] = o;
        }
    }
}

extern "C" void kernel_launch(void* const* d_in, const int* in_sizes, int n_in,
                              void* d_out, int out_size, void* d_ws, size_t ws_size,
                              hipStream_t stream) {
    const float* x        = (const float*)d_in[0];
    const int*   eidx     = (const int*)d_in[1];   // [2, E] flat int32
    const float* W        = (const float*)d_in[2];
    const float* att_src  = (const float*)d_in[3];
    const float* att_dst  = (const float*)d_in[4];
    const float* bias     = (const float*)d_in[5];
    float* out = (float*)d_out;

    const int N = in_sizes[0] / IN_F;
    const int E = in_sizes[1] / 2;
    const int* src = eidx;
    const int* dst = eidx + E;

    const int NB  = (N + BK - 1) >> BK_SHIFT;    // 1563 buckets

    // Workspace (4 B elems, ~24 MB)
    int* u = (int*)d_ws;
    size_t o = 0;
    __half2* h2     = (__half2*)(u + o); o += (size_t)(N + 1) * 16;   // +sentinel row
    float*   asrc   = (float*)(u + o);   o += N + 1;                  // +sentinel
    float*   adst   = (float*)(u + o);   o += N;
    int*     cursor = u + o;             o += (size_t)NBMAX * NSUB;   // 32K counters
    int*     recs   = u + o;             o += (size_t)NBMAX << REGSHIFT;

    const int PB = (N + 63) / 64;                // MFMA proj blocks (64 nodes/block)

    hipMemsetAsync(cursor, 0, (size_t)NBMAX * NSUB * sizeof(int), stream);
    k_projpart<<<PB + NPART + 1, 256, 0, stream>>>(x, W, att_src, att_dst,
                                                   h2, asrc, adst, src, dst,
                                                   cursor, recs, N, E, PB);
    k_pg<<<NB, 512, 0, stream>>>(recs, cursor, asrc, adst, h2, bias, out, NB, E, N);
}

// Round 14
// 204.039 us; speedup vs baseline: 1.8090x; 1.0553x over previous
//
#include <hip/hip_runtime.h>
#include <hip/hip_fp16.h>
#include <math.h>

#define IN_F 64
#define OUT_F 32
#define NEG_SLOPE 0.2f

#define BK_SHIFT 6
#define BK 64            // nodes per bucket
#define NBMAX 2048       // max buckets (N <= 131072)
#define NPART 2048       // partition-role blocks (fused into k_projpart)
#define NSUB 16          // sub-cursors per bucket
#define SUBSHIFT 7
#define SUBCAP 128       // slots per sub-region (Poisson mean 64, +8 sigma)
#define REGSHIFT 11      // bucket region = NSUB*SUBCAP = 2048 ints
#define CURSHIFT 4       // each sub-cursor padded to its own 64B cache line
#define PSTAGE 4         // 512 thr x 4 = 2048 = max records per bucket region
#define COLCAP 2304      // LDS col capacity (2048 + pad slack 192, rounded up)

typedef _Float16 half8_t __attribute__((ext_vector_type(8)));
typedef float float4_t __attribute__((ext_vector_type(4)));
typedef int int4_t __attribute__((ext_vector_type(4)));

// SESSION FINDINGS:
//  - gfx950 LDS atomics ~4.2 cy per LANE-op. 1-2/edge max.
//  - gfx950 device atomics serialize TWO-TIER: ~240ns per same-ADDRESS op
//    (r12: 1024-deep = 245us) AND ~96ns per same-CACHE-LINE op (r13: 16
//    sub-cursors in one 64B line, 1024 ops/line = 98us). Budget <=64 ops
//    per address AND per line. r14: pad each sub-cursor to its own line.
//  - k_pg at its DS+VMEM overlap floor (~44us).

__device__ __forceinline__ float leaky(float v) {
    return (v > 0.0f) ? v : NEG_SLOPE * v;
}

// Inclusive block scan, 512 threads. wsum: >=8-int LDS scratch.
__device__ __forceinline__ int incScan512(int v, int tid, int* wsum) {
    const int lane = tid & 63, wid = tid >> 6;
    #pragma unroll
    for (int m = 1; m < 64; m <<= 1) {
        int u = __shfl_up(v, m);
        if (lane >= m) v += u;
    }
    if (lane == 63) wsum[wid] = v;
    __syncthreads();
    int add = 0;
    for (int k = 0; k < wid; ++k) add += wsum[k];
    __syncthreads();
    return v + add;
}

// Fused projection + partition.
// Blocks [0, PB): MFMA projection (16 nodes/wave, 64/block, no LDS).
// Blocks [PB, PB+NPART): sub-cursor direct reservation: per edge ONE global
//   atomicAdd(cursor[(b*NSUB+j)<<CURSHIFT],1), j=(e>>8)&15 — each counter on
//   its own 64B line (<=64 ops per line) — + packed-record store.
// Block PB+NPART: gather sentinel init (h2 row N = 0, asrc[N] = -1e30).
__global__ __launch_bounds__(256) void k_projpart(
        const float* __restrict__ x, const float* __restrict__ W,
        const float* __restrict__ att_src, const float* __restrict__ att_dst,
        __half2* __restrict__ h2, float* __restrict__ asrc, float* __restrict__ adst,
        const int* __restrict__ src, const int* __restrict__ dst,
        int* __restrict__ cursor, int* __restrict__ recs,
        int N, int E, int PB) {
    const int tid = threadIdx.x;

    if (blockIdx.x >= PB + NPART) {
        // ---- sentinel init role ----
        if (tid < 16) h2[(size_t)N * 16 + tid] = __floats2half2_rn(0.0f, 0.0f);
        if (tid == 16) asrc[N] = -1e30f;
        return;
    }
    if (blockIdx.x >= PB) {
        // ---- partition role ----
        const int blk = blockIdx.x - PB;
        for (int e = blk * 256 + tid; e < E; e += NPART * 256) {
            const int s = src[e];
            const int d = dst[e];
            const int b = d >> BK_SHIFT;
            const int j = (e >> 8) & (NSUB - 1);
            const int idx = atomicAdd(&cursor[(b * NSUB + j) << CURSHIFT], 1);
            if (idx < SUBCAP)
                recs[((size_t)b << REGSHIFT) + (j << SUBSHIFT) + idx] =
                    ((d & (BK - 1)) << 17) | s;
        }
        return;
    }

    // ---- MFMA projection role ----
    const int wv   = tid >> 6;               // wave 0..3
    const int lane = tid & 63;
    const int m    = lane & 15;              // node-in-16 (A) / channel-in-group (B, C/D)
    const int quad = lane >> 4;              // 0..3
    const int node0 = (blockIdx.x * 4 + wv) * 16;
    if (node0 >= N) return;

    const int kb = quad * 8;
    // B fragments (W is 64x32, row-major W[k*32+c]); built once, L2-hot.
    half8_t b00, b01, b10, b11;
    #pragma unroll
    for (int j = 0; j < 8; ++j) {
        b00[j] = (_Float16)W[(kb + j) * OUT_F + m];
        b01[j] = (_Float16)W[(32 + kb + j) * OUT_F + m];
        b10[j] = (_Float16)W[(kb + j) * OUT_F + 16 + m];
        b11[j] = (_Float16)W[(32 + kb + j) * OUT_F + 16 + m];
    }
    // A fragments: x row (clamped in the tail block), 2x float4 per K-chunk.
    const int row = min(node0 + m, N - 1);
    const float* xr = x + (size_t)row * IN_F + kb;
    float4_t xa = *(const float4_t*)(xr);
    float4_t xb = *(const float4_t*)(xr + 4);
    float4_t xc = *(const float4_t*)(xr + 32);
    float4_t xd = *(const float4_t*)(xr + 36);
    half8_t a0, a1;
    #pragma unroll
    for (int j = 0; j < 4; ++j) {
        a0[j] = (_Float16)xa[j]; a0[4 + j] = (_Float16)xb[j];
        a1[j] = (_Float16)xc[j]; a1[4 + j] = (_Float16)xd[j];
    }
    float4_t acc0 = {0.f, 0.f, 0.f, 0.f};
    float4_t acc1 = {0.f, 0.f, 0.f, 0.f};
    acc0 = __builtin_amdgcn_mfma_f32_16x16x32_f16(a0, b00, acc0, 0, 0, 0);
    acc0 = __builtin_amdgcn_mfma_f32_16x16x32_f16(a1, b01, acc0, 0, 0, 0);
    acc1 = __builtin_amdgcn_mfma_f32_16x16x32_f16(a0, b10, acc1, 0, 0, 0);
    acc1 = __builtin_amdgcn_mfma_f32_16x16x32_f16(a1, b11, acc1, 0, 0, 0);

    // Epilogue: h2 (fp16 pairs) + asrc/adst per node.
    const float aS0 = att_src[m], aS1 = att_src[16 + m];
    const float aD0 = att_dst[m], aD1 = att_dst[16 + m];
    #pragma unroll
    for (int r = 0; r < 4; ++r) {
        const int node = node0 + quad * 4 + r;
        float h0 = acc0[r], h1 = acc1[r];
        float h0p = __shfl_xor(h0, 1);
        float h1p = __shfl_xor(h1, 1);
        if (node < N && (m & 1) == 0) {
            __half2 hv;
            hv.x = __float2half_rn(h0); hv.y = __float2half_rn(h0p);
            h2[(size_t)node * 16 + (m >> 1)] = hv;
            __half2 hw;
            hw.x = __float2half_rn(h1); hw.y = __float2half_rn(h1p);
            h2[(size_t)node * 16 + 8 + (m >> 1)] = hw;
        }
        float vs = h0 * aS0 + h1 * aS1;
        float vd = h0 * aD0 + h1 * aD1;
        #pragma unroll
        for (int mm = 1; mm < 16; mm <<= 1) {
            vs += __shfl_xor(vs, mm);
            vd += __shfl_xor(vd, mm);
        }
        if (node < N && m == 0) {
            asrc[node] = vs;
            adst[node] = vd;
        }
    }
}

// Fused place+gather: one block per bucket (64 nodes, 512 threads = 8 waves).
// Records live in 16 sub-regions of 128 slots; valid prefix per sub-region =
// min(cursor[(b*16+j)<<4], 128). 16-entry prefix + 4-step binary search maps
// flat index -> (sub-region, offset). Phase 1 (place): fine histogram; padded
// (x4) scan; place col into sentinel-prefilled LDS. Phase 2 (gather): wave w
// handles nodes w*8..w*8+7; 4x16-lane groups gather h2/asrc from global.
__global__ __launch_bounds__(512) void k_pg(const int* __restrict__ recs,
                                            const int* __restrict__ cursor,
                                            const float* __restrict__ asrc,
                                            const float* __restrict__ adst,
                                            const __half2* __restrict__ h2,
                                            const float* __restrict__ bias,
                                            float* __restrict__ out,
                                            int NB, int E, int N) {
    __shared__ __align__(16) int colsh[COLCAP];
    __shared__ int fineCnt[BK];
    __shared__ int cur[BK];
    __shared__ int loff[BK];
    __shared__ int lpad[BK];
    __shared__ int pre[NSUB + 1];
    __shared__ int wsum[8];
    const int b = blockIdx.x, tid = threadIdx.x;
    const int node0 = b << BK_SHIFT;
    const size_t rb = (size_t)b << REGSHIFT;

    // ---- init: sub-count prefix + sentinel prefill + zero counts ----
    if (tid == 0) {
        int a = 0;
        #pragma unroll
        for (int j = 0; j < NSUB; ++j) {
            pre[j] = a;
            a += min(cursor[(b * NSUB + j) << CURSHIFT], SUBCAP);
        }
        pre[NSUB] = a;
    }
    for (int i = tid; i < COLCAP; i += 512) colsh[i] = N;
    if (tid < BK) fineCnt[tid] = 0;
    __syncthreads();
    const int total = pre[NSUB];

    // ---- fine histogram (register-staged; flat idx -> sub-region via search) ----
    int myrec[PSTAGE];
    #pragma unroll
    for (int k = 0; k < PSTAGE; ++k) {
        int i = tid + k * 512;
        if (i < total) {
            int lo = 0;
            #pragma unroll
            for (int st = 8; st >= 1; st >>= 1)
                if (pre[lo + st] <= i) lo += st;
            int v = recs[rb + (lo << SUBSHIFT) + (i - pre[lo])];
            myrec[k] = v;
            atomicAdd(&fineCnt[v >> 17], 1);
        }
    }
    __syncthreads();

    // ---- padded (x4) scan of per-node counts ----
    const int v0 = (tid < BK) ? fineCnt[tid] : 0;
    const int pv = (v0 + 3) & ~3;
    const int vin = (tid < BK) ? pv : 0;
    const int pinc = incScan512(vin, tid, wsum);
    const int pexcl = pinc - vin;
    if (tid < BK) {
        loff[tid] = pexcl;       // multiple of 4 -> 16B-aligned chunks
        lpad[tid] = pv;
        cur[tid]  = pexcl;
    }
    __syncthreads();

    // ---- place into LDS col ----
    #pragma unroll
    for (int k = 0; k < PSTAGE; ++k) {
        int i = tid + k * 512;
        if (i < total) {
            int r = myrec[k];
            int p = atomicAdd(&cur[r >> 17], 1);
            colsh[p] = r & 0x1FFFF;
        }
    }
    __syncthreads();

    // ---- gather: wave w -> nodes node0 + w*8 .. +7 ----
    const int wid  = tid >> 6;
    const int lane = tid & 63;
    const int g    = lane >> 4;      // edge group 0..3
    const int c2   = lane & 15;      // half2 channel pair
    for (int i = 0; i < 8; ++i) {
        const int dloc = wid * 8 + i;
        const int n = node0 + dloc;
        if (n >= N) break;           // only the tail bucket; uniform per wave
        const float adst_n = adst[n];
        float l = 0.0f, accx = 0.0f, accy = 0.0f;
        if (g == 0) {                // self loop
            float p = __expf(leaky(asrc[n] + adst_n));
            float2 hv = __half22float2(h2[(size_t)n * 16 + c2]);
            l = p; accx = p * hv.x; accy = p * hv.y;
        }
        const int base = loff[dloc];
        const int nch  = lpad[dloc] >> 2;    // 4-edge chunks
        for (int c = g; c < nch; c += 4) {   // clamp-free (sentinel-padded x4)
            const int4_t cc = *(const int4_t*)(&colsh[base + c * 4]);
            const int s0 = cc[0], s1 = cc[1], s2 = cc[2], s3 = cc[3];
            float a0 = asrc[s0], a1 = asrc[s1], a2 = asrc[s2], a3 = asrc[s3];
            float2 h0 = __half22float2(h2[(size_t)s0 * 16 + c2]);
            float2 h1 = __half22float2(h2[(size_t)s1 * 16 + c2]);
            float2 hv2 = __half22float2(h2[(size_t)s2 * 16 + c2]);
            float2 h3 = __half22float2(h2[(size_t)s3 * 16 + c2]);
            float p0 = __expf(leaky(a0 + adst_n));
            float p1 = __expf(leaky(a1 + adst_n));
            float p2 = __expf(leaky(a2 + adst_n));
            float p3 = __expf(leaky(a3 + adst_n));
            l += (p0 + p1) + (p2 + p3);
            accx += p0 * h0.x + p1 * h1.x + p2 * hv2.x + p3 * h3.x;
            accy += p0 * h0.y + p1 * h1.y + p2 * hv2.y + p3 * h3.y;
        }
        l    += __shfl_xor(l, 16);    l    += __shfl_xor(l, 32);
        accx += __shfl_xor(accx, 16); accx += __shfl_xor(accx, 32);
        accy += __shfl_xor(accy, 16); accy += __shfl_xor(accy, 32);
        if (g == 0) {
            float inv = 1.0f / l;
            float2 bb = ((const float2*)bias)[c2];
            float2 o;
            o.x = fmaxf(accx * inv + bb.x, 0.0f);
            o.y = fmaxf(accy * inv + bb.y, 0.0f);
            ((float2*)out)[(size_t)n * 16 + c2] = o;
        }
    }
}

extern "C" void kernel_launch(void* const* d_in, const int* in_sizes, int n_in,
                              void* d_out, int out_size, void* d_ws, size_t ws_size,
                              hipStream_t stream) {
    const float* x        = (const float*)d_in[0];
    const int*   eidx     = (const int*)d_in[1];   // [2, E] flat int32
    const float* W        = (const float*)d_in[2];
    const float* att_src  = (const float*)d_in[3];
    const float* att_dst  = (const float*)d_in[4];
    const float* bias     = (const float*)d_in[5];
    float* out = (float*)d_out;

    const int N = in_sizes[0] / IN_F;
    const int E = in_sizes[1] / 2;
    const int* src = eidx;
    const int* dst = eidx + E;

    const int NB  = (N + BK - 1) >> BK_SHIFT;    // 1563 buckets

    // Workspace (4 B elems, ~32 MB)
    int* u = (int*)d_ws;
    size_t o = 0;
    __half2* h2     = (__half2*)(u + o); o += (size_t)(N + 1) * 16;   // +sentinel row
    float*   asrc   = (float*)(u + o);   o += N + 1;                  // +sentinel
    float*   adst   = (float*)(u + o);   o += N;
    int*     cursor = u + o;             o += ((size_t)NBMAX * NSUB) << CURSHIFT; // line-padded
    int*     recs   = u + o;             o += (size_t)NBMAX << REGSHIFT;

    const int PB = (N + 63) / 64;                // MFMA proj blocks (64 nodes/block)

    hipMemsetAsync(cursor, 0, (((size_t)NB * NSUB) << CURSHIFT) * sizeof(int), stream);
    k_projpart<<<PB + NPART + 1, 256, 0, stream>>>(x, W, att_src, att_dst,
                                                   h2, asrc, adst, src, dst,
                                                   cursor, recs, N, E, PB);
    k_pg<<<NB, 512, 0, stream>>>(recs, cursor, asrc, adst, h2, bias, out, NB, E, N);
}

// Round 15
// 160.034 us; speedup vs baseline: 2.3065x; 1.2750x over previous
//
#include <hip/hip_runtime.h>
#include <hip/hip_fp16.h>
#include <math.h>

#define IN_F 64
#define OUT_F 32
#define NEG_SLOPE 0.2f

#define BK_SHIFT 6
#define BK 64            // nodes per bucket
#define NBMAX 2048       // max buckets (N <= 131072)
#define NBLKA 256        // bpart-role blocks
#define CAPSHIFT 11
#define CAP 2048         // fixed recs capacity per bucket (mean 1024, sd 32)
#define PSTAGE 4         // 512 thr x 4 = 2048 = CAP
#define COLCAP 2304      // LDS col capacity (2048 + pad slack)

typedef _Float16 half8_t __attribute__((ext_vector_type(8)));
typedef float float4_t __attribute__((ext_vector_type(4)));
typedef int int4_t __attribute__((ext_vector_type(4)));

// SESSION FINDINGS:
//  - gfx950 LDS atomics ~4.2 cy per LANE-op. 1-2/edge max.
//  - gfx950 device atomics: ~240ns per same-ADDRESS op, ~96ns per same-LINE
//    op (r12/r13). Scattered per-edge 4B global stores cost ~64B line
//    write-allocate each (r14: 84us, WRITE 64MB). Partition records must be
//    written via LDS-cursored mostly-contiguous runs (r11 structure).
//  - k_pg at its DS+VMEM overlap floor (~44us).
//  - r15: proj and bpart are independent -> fused into one kernel (1820
//    blocks, all co-resident) so bpart's latency hides under proj's compute.

__device__ __forceinline__ float leaky(float v) {
    return (v > 0.0f) ? v : NEG_SLOPE * v;
}

// Inclusive block scan, 512 threads. wsum: >=8-int LDS scratch.
__device__ __forceinline__ int incScan512(int v, int tid, int* wsum) {
    const int lane = tid & 63, wid = tid >> 6;
    #pragma unroll
    for (int m = 1; m < 64; m <<= 1) {
        int u = __shfl_up(v, m);
        if (lane >= m) v += u;
    }
    if (lane == 63) wsum[wid] = v;
    __syncthreads();
    int add = 0;
    for (int k = 0; k < wid; ++k) add += wsum[k];
    __syncthreads();
    return v + add;
}

// Fused projection + bucket partition.
// Blocks [0, PB): MFMA projection (16 nodes/wave, 64 nodes/block, no LDS).
// Blocks [PB, PB+NBLKA): two-pass LDS partition (r11 structure): count this
//   block's edge slice per bucket in LDS; reserve a contiguous chunk per
//   non-empty bucket via ONE global atomicAdd(cursor[b], c) (cursor pure
//   count; base b<<CAPSHIFT added locally; reserve loop rotation-staggered
//   to de-burst same-address chains); place records via LDS cursors.
// Block PB+NBLKA: gather sentinel init (h2 row N = 0, asrc[N] = -1e30).
__global__ __launch_bounds__(256) void k_projbpart(
        const float* __restrict__ x, const float* __restrict__ W,
        const float* __restrict__ att_src, const float* __restrict__ att_dst,
        __half2* __restrict__ h2, float* __restrict__ asrc, float* __restrict__ adst,
        const int* __restrict__ src, const int* __restrict__ dst,
        int* __restrict__ cursor, int* __restrict__ recs,
        int N, int NB, int E, int epb, int PB) {
    __shared__ int smem[2 * NBMAX];          // 16 KB (partition role only)
    const int tid = threadIdx.x;

    if (blockIdx.x >= PB + NBLKA) {
        // ---- sentinel init role ----
        if (tid < 16) h2[(size_t)N * 16 + tid] = __floats2half2_rn(0.0f, 0.0f);
        if (tid == 16) asrc[N] = -1e30f;
        return;
    }
    if (blockIdx.x >= PB) {
        // ---- partition role ----
        int* cnt  = smem;
        int* lcur = smem + NBMAX;
        const int blk = blockIdx.x - PB;
        for (int b = tid; b < NB; b += 256) cnt[b] = 0;
        __syncthreads();
        const int e0 = blk * epb, e1 = min(E, e0 + epb);
        for (int e = e0 + tid; e < e1; e += 256)
            atomicAdd(&cnt[dst[e] >> BK_SHIFT], 1);
        __syncthreads();
        const int off = (blk * 389) % NB;            // stagger same-address chains
        for (int i = tid; i < NB; i += 256) {
            int b = i + off; if (b >= NB) b -= NB;
            const int c = cnt[b];
            if (c > 0) lcur[b] = (b << CAPSHIFT) + atomicAdd(&cursor[b], c);
        }
        __syncthreads();
        for (int e = e0 + tid; e < e1; e += 256) {
            int s = src[e];
            int d = dst[e];
            int p = atomicAdd(&lcur[d >> BK_SHIFT], 1);   // LDS cursor
            recs[p] = ((d & (BK - 1)) << 17) | s;
        }
        return;
    }

    // ---- MFMA projection role ----
    const int wv   = tid >> 6;               // wave 0..3
    const int lane = tid & 63;
    const int m    = lane & 15;              // node-in-16 (A) / channel-in-group (B, C/D)
    const int quad = lane >> 4;              // 0..3
    const int node0 = (blockIdx.x * 4 + wv) * 16;
    if (node0 >= N) return;

    const int kb = quad * 8;
    // B fragments (W is 64x32, row-major W[k*32+c]); built once, L2-hot.
    half8_t b00, b01, b10, b11;
    #pragma unroll
    for (int j = 0; j < 8; ++j) {
        b00[j] = (_Float16)W[(kb + j) * OUT_F + m];
        b01[j] = (_Float16)W[(32 + kb + j) * OUT_F + m];
        b10[j] = (_Float16)W[(kb + j) * OUT_F + 16 + m];
        b11[j] = (_Float16)W[(32 + kb + j) * OUT_F + 16 + m];
    }
    // A fragments: x row (clamped in the tail block), 2x float4 per K-chunk.
    const int row = min(node0 + m, N - 1);
    const float* xr = x + (size_t)row * IN_F + kb;
    float4_t xa = *(const float4_t*)(xr);
    float4_t xb = *(const float4_t*)(xr + 4);
    float4_t xc = *(const float4_t*)(xr + 32);
    float4_t xd = *(const float4_t*)(xr + 36);
    half8_t a0, a1;
    #pragma unroll
    for (int j = 0; j < 4; ++j) {
        a0[j] = (_Float16)xa[j]; a0[4 + j] = (_Float16)xb[j];
        a1[j] = (_Float16)xc[j]; a1[4 + j] = (_Float16)xd[j];
    }
    float4_t acc0 = {0.f, 0.f, 0.f, 0.f};
    float4_t acc1 = {0.f, 0.f, 0.f, 0.f};
    acc0 = __builtin_amdgcn_mfma_f32_16x16x32_f16(a0, b00, acc0, 0, 0, 0);
    acc0 = __builtin_amdgcn_mfma_f32_16x16x32_f16(a1, b01, acc0, 0, 0, 0);
    acc1 = __builtin_amdgcn_mfma_f32_16x16x32_f16(a0, b10, acc1, 0, 0, 0);
    acc1 = __builtin_amdgcn_mfma_f32_16x16x32_f16(a1, b11, acc1, 0, 0, 0);

    // Epilogue: h2 (fp16 pairs) + asrc/adst per node.
    const float aS0 = att_src[m], aS1 = att_src[16 + m];
    const float aD0 = att_dst[m], aD1 = att_dst[16 + m];
    #pragma unroll
    for (int r = 0; r < 4; ++r) {
        const int node = node0 + quad * 4 + r;
        float h0 = acc0[r], h1 = acc1[r];
        float h0p = __shfl_xor(h0, 1);
        float h1p = __shfl_xor(h1, 1);
        if (node < N && (m & 1) == 0) {
            __half2 hv;
            hv.x = __float2half_rn(h0); hv.y = __float2half_rn(h0p);
            h2[(size_t)node * 16 + (m >> 1)] = hv;
            __half2 hw;
            hw.x = __float2half_rn(h1); hw.y = __float2half_rn(h1p);
            h2[(size_t)node * 16 + 8 + (m >> 1)] = hw;
        }
        float vs = h0 * aS0 + h1 * aS1;
        float vd = h0 * aD0 + h1 * aD1;
        #pragma unroll
        for (int mm = 1; mm < 16; mm <<= 1) {
            vs += __shfl_xor(vs, mm);
            vd += __shfl_xor(vd, mm);
        }
        if (node < N && m == 0) {
            asrc[node] = vs;
            adst[node] = vd;
        }
    }
}

// Fused place+gather: one block per bucket (64 nodes, 512 threads = 8 waves).
// cb0 = b*CAP; count = cursor[b] (pure count). Phase 1 (place): fine
// histogram; padded (x4) scan; place col into sentinel-prefilled LDS.
// Phase 2 (gather): wave w handles nodes w*8..w*8+7; 4x16-lane groups read
// chunk lists from LDS and gather h2/asrc from global.
__global__ __launch_bounds__(512) void k_pg(const int* __restrict__ recs,
                                            const int* __restrict__ cursor,
                                            const float* __restrict__ asrc,
                                            const float* __restrict__ adst,
                                            const __half2* __restrict__ h2,
                                            const float* __restrict__ bias,
                                            float* __restrict__ out,
                                            int NB, int E, int N) {
    __shared__ __align__(16) int colsh[COLCAP];
    __shared__ int fineCnt[BK];
    __shared__ int cur[BK];
    __shared__ int loff[BK];
    __shared__ int lpad[BK];
    __shared__ int wsum[8];
    const int b = blockIdx.x, tid = threadIdx.x;
    const int node0 = b << BK_SHIFT;

    const size_t cb0 = (size_t)b << CAPSHIFT;
    const int count = min(cursor[b], CAP);

    // ---- init: sentinel prefill + zero counts ----
    for (int i = tid; i < COLCAP; i += 512) colsh[i] = N;
    if (tid < BK) fineCnt[tid] = 0;
    __syncthreads();

    // ---- fine histogram (register-staged) ----
    int myrec[PSTAGE];
    #pragma unroll
    for (int k = 0; k < PSTAGE; ++k) {
        int i = tid + k * 512;
        if (i < count) {
            int v = recs[cb0 + i];
            myrec[k] = v;
            atomicAdd(&fineCnt[v >> 17], 1);
        }
    }
    __syncthreads();

    // ---- padded (x4) scan of per-node counts ----
    const int v0 = (tid < BK) ? fineCnt[tid] : 0;
    const int pv = (v0 + 3) & ~3;
    const int vin = (tid < BK) ? pv : 0;
    const int pinc = incScan512(vin, tid, wsum);
    const int pexcl = pinc - vin;
    if (tid < BK) {
        loff[tid] = pexcl;       // multiple of 4 -> 16B-aligned chunks
        lpad[tid] = pv;
        cur[tid]  = pexcl;
    }
    __syncthreads();

    // ---- place into LDS col ----
    #pragma unroll
    for (int k = 0; k < PSTAGE; ++k) {
        int i = tid + k * 512;
        if (i < count) {
            int r = myrec[k];
            int p = atomicAdd(&cur[r >> 17], 1);
            colsh[p] = r & 0x1FFFF;
        }
    }
    __syncthreads();

    // ---- gather: wave w -> nodes node0 + w*8 .. +7 ----
    const int wid  = tid >> 6;
    const int lane = tid & 63;
    const int g    = lane >> 4;      // edge group 0..3
    const int c2   = lane & 15;      // half2 channel pair
    for (int i = 0; i < 8; ++i) {
        const int dloc = wid * 8 + i;
        const int n = node0 + dloc;
        if (n >= N) break;           // only the tail bucket; uniform per wave
        const float adst_n = adst[n];
        float l = 0.0f, accx = 0.0f, accy = 0.0f;
        if (g == 0) {                // self loop
            float p = __expf(leaky(asrc[n] + adst_n));
            float2 hv = __half22float2(h2[(size_t)n * 16 + c2]);
            l = p; accx = p * hv.x; accy = p * hv.y;
        }
        const int base = loff[dloc];
        const int nch  = lpad[dloc] >> 2;    // 4-edge chunks
        for (int c = g; c < nch; c += 4) {   // clamp-free (sentinel-padded x4)
            const int4_t cc = *(const int4_t*)(&colsh[base + c * 4]);
            const int s0 = cc[0], s1 = cc[1], s2 = cc[2], s3 = cc[3];
            float a0 = asrc[s0], a1 = asrc[s1], a2 = asrc[s2], a3 = asrc[s3];
            float2 h0 = __half22float2(h2[(size_t)s0 * 16 + c2]);
            float2 h1 = __half22float2(h2[(size_t)s1 * 16 + c2]);
            float2 hv2 = __half22float2(h2[(size_t)s2 * 16 + c2]);
            float2 h3 = __half22float2(h2[(size_t)s3 * 16 + c2]);
            float p0 = __expf(leaky(a0 + adst_n));
            float p1 = __expf(leaky(a1 + adst_n));
            float p2 = __expf(leaky(a2 + adst_n));
            float p3 = __expf(leaky(a3 + adst_n));
            l += (p0 + p1) + (p2 + p3);
            accx += p0 * h0.x + p1 * h1.x + p2 * hv2.x + p3 * h3.x;
            accy += p0 * h0.y + p1 * h1.y + p2 * hv2.y + p3 * h3.y;
        }
        l    += __shfl_xor(l, 16);    l    += __shfl_xor(l, 32);
        accx += __shfl_xor(accx, 16); accx += __shfl_xor(accx, 32);
        accy += __shfl_xor(accy, 16); accy += __shfl_xor(accy, 32);
        if (g == 0) {
            float inv = 1.0f / l;
            float2 bb = ((const float2*)bias)[c2];
            float2 o;
            o.x = fmaxf(accx * inv + bb.x, 0.0f);
            o.y = fmaxf(accy * inv + bb.y, 0.0f);
            ((float2*)out)[(size_t)n * 16 + c2] = o;
        }
    }
}

extern "C" void kernel_launch(void* const* d_in, const int* in_sizes, int n_in,
                              void* d_out, int out_size, void* d_ws, size_t ws_size,
                              hipStream_t stream) {
    const float* x        = (const float*)d_in[0];
    const int*   eidx     = (const int*)d_in[1];   // [2, E] flat int32
    const float* W        = (const float*)d_in[2];
    const float* att_src  = (const float*)d_in[3];
    const float* att_dst  = (const float*)d_in[4];
    const float* bias     = (const float*)d_in[5];
    float* out = (float*)d_out;

    const int N = in_sizes[0] / IN_F;
    const int E = in_sizes[1] / 2;
    const int* src = eidx;
    const int* dst = eidx + E;

    const int NB  = (N + BK - 1) >> BK_SHIFT;    // 1563 buckets
    const int epb = (E + NBLKA - 1) / NBLKA;     // edges per partition block

    // Workspace (4 B elems, ~23 MB)
    int* u = (int*)d_ws;
    size_t o = 0;
    __half2* h2     = (__half2*)(u + o); o += (size_t)(N + 1) * 16;   // +sentinel row
    float*   asrc   = (float*)(u + o);   o += N + 1;                  // +sentinel
    float*   adst   = (float*)(u + o);   o += N;
    int*     cursor = u + o;             o += NBMAX;
    int*     recs   = u + o;             o += (size_t)NBMAX << CAPSHIFT;

    const int PB = (N + 63) / 64;                // MFMA proj blocks (64 nodes/block)

    hipMemsetAsync(cursor, 0, NBMAX * sizeof(int), stream);
    k_projbpart<<<PB + NBLKA + 1, 256, 0, stream>>>(x, W, att_src, att_dst,
                                                    h2, asrc, adst, src, dst,
                                                    cursor, recs, N, NB, E, epb, PB);
    k_pg<<<NB, 512, 0, stream>>>(recs, cursor, asrc, adst, h2, bias, out, NB, E, N);
}

// Round 16
// 154.446 us; speedup vs baseline: 2.3899x; 1.0362x over previous
//
#include <hip/hip_runtime.h>
#include <hip/hip_fp16.h>
#include <math.h>

#define IN_F 64
#define OUT_F 32
#define NEG_SLOPE 0.2f

#define BK_SHIFT 6
#define BK 64            // nodes per bucket
#define NBMAX 2048       // max buckets (N <= 131072)
#define NBLKA 256        // bpart-role blocks
#define CAPSHIFT 11
#define CAP 2048         // fixed recs capacity per bucket (mean 1024, sd 32)
#define PSTAGE 4         // 512 thr x 4 = 2048 = CAP
#define COLCAP 2304      // LDS col capacity (2048 + pad slack)

typedef _Float16 half8_t __attribute__((ext_vector_type(8)));
typedef float float4_t __attribute__((ext_vector_type(4)));
typedef int int4_t __attribute__((ext_vector_type(4)));

// SESSION FINDINGS:
//  - gfx950 LDS atomics ~4.2 cy per LANE-op. 1-2/edge max.
//  - gfx950 device atomics: ~240ns per same-ADDRESS op, ~96ns per same-LINE
//    op (r12/r13). Scattered per-edge 4B global stores cost ~64B line
//    write-allocate each (r14). Partition records written via LDS-cursored
//    mostly-contiguous runs (r11 structure).
//  - proj+bpart fusion: 85us serialized -> ~52us fused (r15).
//  - hipMemsetAsync inside kernel_launch costs ~50-70us of WALL overhead per
//    iteration (r12-r15 all show the gap; memset-free rounds don't) —
//    harness graph fast-path disruption. Zero workspace via a tiny kernel.

__device__ __forceinline__ float leaky(float v) {
    return (v > 0.0f) ? v : NEG_SLOPE * v;
}

// Inclusive block scan, 512 threads. wsum: >=8-int LDS scratch.
__device__ __forceinline__ int incScan512(int v, int tid, int* wsum) {
    const int lane = tid & 63, wid = tid >> 6;
    #pragma unroll
    for (int m = 1; m < 64; m <<= 1) {
        int u = __shfl_up(v, m);
        if (lane >= m) v += u;
    }
    if (lane == 63) wsum[wid] = v;
    __syncthreads();
    int add = 0;
    for (int k = 0; k < wid; ++k) add += wsum[k];
    __syncthreads();
    return v + add;
}

// Tiny init: zero bucket cursors + gather sentinel (h2 row N = 0,
// asrc[N] = -1e30 => p = 0). Replaces hipMemsetAsync (graph-unfriendly).
__global__ __launch_bounds__(512) void k_zero(int* __restrict__ cursor,
                                              __half2* __restrict__ h2,
                                              float* __restrict__ asrc, int N) {
    const int tid = threadIdx.x;
    #pragma unroll
    for (int k = 0; k < NBMAX / 512; ++k) cursor[tid + k * 512] = 0;
    if (tid < 16) h2[(size_t)N * 16 + tid] = __floats2half2_rn(0.0f, 0.0f);
    if (tid == 16) asrc[N] = -1e30f;
}

// Fused projection + bucket partition.
// Blocks [0, PB): MFMA projection (16 nodes/wave, 64 nodes/block, no LDS).
// Blocks [PB, PB+NBLKA): two-pass LDS partition (r11 structure): count this
//   block's edge slice per bucket in LDS; reserve a contiguous chunk per
//   non-empty bucket via ONE global atomicAdd(cursor[b], c) (rotation-
//   staggered to de-burst same-address chains); place records via LDS cursors.
__global__ __launch_bounds__(256) void k_projbpart(
        const float* __restrict__ x, const float* __restrict__ W,
        const float* __restrict__ att_src, const float* __restrict__ att_dst,
        __half2* __restrict__ h2, float* __restrict__ asrc, float* __restrict__ adst,
        const int* __restrict__ src, const int* __restrict__ dst,
        int* __restrict__ cursor, int* __restrict__ recs,
        int N, int NB, int E, int epb, int PB) {
    __shared__ int smem[2 * NBMAX];          // 16 KB (partition role only)
    const int tid = threadIdx.x;

    if (blockIdx.x >= PB) {
        // ---- partition role ----
        int* cnt  = smem;
        int* lcur = smem + NBMAX;
        const int blk = blockIdx.x - PB;
        for (int b = tid; b < NB; b += 256) cnt[b] = 0;
        __syncthreads();
        const int e0 = blk * epb, e1 = min(E, e0 + epb);
        for (int e = e0 + tid; e < e1; e += 256)
            atomicAdd(&cnt[dst[e] >> BK_SHIFT], 1);
        __syncthreads();
        const int off = (blk * 389) % NB;            // stagger same-address chains
        for (int i = tid; i < NB; i += 256) {
            int b = i + off; if (b >= NB) b -= NB;
            const int c = cnt[b];
            if (c > 0) lcur[b] = (b << CAPSHIFT) + atomicAdd(&cursor[b], c);
        }
        __syncthreads();
        for (int e = e0 + tid; e < e1; e += 256) {
            int s = src[e];
            int d = dst[e];
            int p = atomicAdd(&lcur[d >> BK_SHIFT], 1);   // LDS cursor
            recs[p] = ((d & (BK - 1)) << 17) | s;
        }
        return;
    }

    // ---- MFMA projection role ----
    const int wv   = tid >> 6;               // wave 0..3
    const int lane = tid & 63;
    const int m    = lane & 15;              // node-in-16 (A) / channel-in-group (B, C/D)
    const int quad = lane >> 4;              // 0..3
    const int node0 = (blockIdx.x * 4 + wv) * 16;
    if (node0 >= N) return;

    const int kb = quad * 8;
    // B fragments (W is 64x32, row-major W[k*32+c]); built once, L2-hot.
    half8_t b00, b01, b10, b11;
    #pragma unroll
    for (int j = 0; j < 8; ++j) {
        b00[j] = (_Float16)W[(kb + j) * OUT_F + m];
        b01[j] = (_Float16)W[(32 + kb + j) * OUT_F + m];
        b10[j] = (_Float16)W[(kb + j) * OUT_F + 16 + m];
        b11[j] = (_Float16)W[(32 + kb + j) * OUT_F + 16 + m];
    }
    // A fragments: x row (clamped in the tail block), 2x float4 per K-chunk.
    const int row = min(node0 + m, N - 1);
    const float* xr = x + (size_t)row * IN_F + kb;
    float4_t xa = *(const float4_t*)(xr);
    float4_t xb = *(const float4_t*)(xr + 4);
    float4_t xc = *(const float4_t*)(xr + 32);
    float4_t xd = *(const float4_t*)(xr + 36);
    half8_t a0, a1;
    #pragma unroll
    for (int j = 0; j < 4; ++j) {
        a0[j] = (_Float16)xa[j]; a0[4 + j] = (_Float16)xb[j];
        a1[j] = (_Float16)xc[j]; a1[4 + j] = (_Float16)xd[j];
    }
    float4_t acc0 = {0.f, 0.f, 0.f, 0.f};
    float4_t acc1 = {0.f, 0.f, 0.f, 0.f};
    acc0 = __builtin_amdgcn_mfma_f32_16x16x32_f16(a0, b00, acc0, 0, 0, 0);
    acc0 = __builtin_amdgcn_mfma_f32_16x16x32_f16(a1, b01, acc0, 0, 0, 0);
    acc1 = __builtin_amdgcn_mfma_f32_16x16x32_f16(a0, b10, acc1, 0, 0, 0);
    acc1 = __builtin_amdgcn_mfma_f32_16x16x32_f16(a1, b11, acc1, 0, 0, 0);

    // Epilogue: h2 (fp16 pairs) + asrc/adst per node.
    const float aS0 = att_src[m], aS1 = att_src[16 + m];
    const float aD0 = att_dst[m], aD1 = att_dst[16 + m];
    #pragma unroll
    for (int r = 0; r < 4; ++r) {
        const int node = node0 + quad * 4 + r;
        float h0 = acc0[r], h1 = acc1[r];
        float h0p = __shfl_xor(h0, 1);
        float h1p = __shfl_xor(h1, 1);
        if (node < N && (m & 1) == 0) {
            __half2 hv;
            hv.x = __float2half_rn(h0); hv.y = __float2half_rn(h0p);
            h2[(size_t)node * 16 + (m >> 1)] = hv;
            __half2 hw;
            hw.x = __float2half_rn(h1); hw.y = __float2half_rn(h1p);
            h2[(size_t)node * 16 + 8 + (m >> 1)] = hw;
        }
        float vs = h0 * aS0 + h1 * aS1;
        float vd = h0 * aD0 + h1 * aD1;
        #pragma unroll
        for (int mm = 1; mm < 16; mm <<= 1) {
            vs += __shfl_xor(vs, mm);
            vd += __shfl_xor(vd, mm);
        }
        if (node < N && m == 0) {
            asrc[node] = vs;
            adst[node] = vd;
        }
    }
}

// Fused place+gather: one block per bucket (64 nodes, 512 threads = 8 waves).
// cb0 = b*CAP; count = cursor[b] (pure count). Phase 1 (place): fine
// histogram; padded (x4) scan; place col into sentinel-prefilled LDS.
// Phase 2 (gather): wave w handles nodes w*8..w*8+7; 4x16-lane groups read
// chunk lists from LDS and gather h2/asrc from global.
__global__ __launch_bounds__(512) void k_pg(const int* __restrict__ recs,
                                            const int* __restrict__ cursor,
                                            const float* __restrict__ asrc,
                                            const float* __restrict__ adst,
                                            const __half2* __restrict__ h2,
                                            const float* __restrict__ bias,
                                            float* __restrict__ out,
                                            int NB, int E, int N) {
    __shared__ __align__(16) int colsh[COLCAP];
    __shared__ int fineCnt[BK];
    __shared__ int cur[BK];
    __shared__ int loff[BK];
    __shared__ int lpad[BK];
    __shared__ int wsum[8];
    const int b = blockIdx.x, tid = threadIdx.x;
    const int node0 = b << BK_SHIFT;

    const size_t cb0 = (size_t)b << CAPSHIFT;
    const int count = min(cursor[b], CAP);

    // ---- init: sentinel prefill + zero counts ----
    for (int i = tid; i < COLCAP; i += 512) colsh[i] = N;
    if (tid < BK) fineCnt[tid] = 0;
    __syncthreads();

    // ---- fine histogram (register-staged) ----
    int myrec[PSTAGE];
    #pragma unroll
    for (int k = 0; k < PSTAGE; ++k) {
        int i = tid + k * 512;
        if (i < count) {
            int v = recs[cb0 + i];
            myrec[k] = v;
            atomicAdd(&fineCnt[v >> 17], 1);
        }
    }
    __syncthreads();

    // ---- padded (x4) scan of per-node counts ----
    const int v0 = (tid < BK) ? fineCnt[tid] : 0;
    const int pv = (v0 + 3) & ~3;
    const int vin = (tid < BK) ? pv : 0;
    const int pinc = incScan512(vin, tid, wsum);
    const int pexcl = pinc - vin;
    if (tid < BK) {
        loff[tid] = pexcl;       // multiple of 4 -> 16B-aligned chunks
        lpad[tid] = pv;
        cur[tid]  = pexcl;
    }
    __syncthreads();

    // ---- place into LDS col ----
    #pragma unroll
    for (int k = 0; k < PSTAGE; ++k) {
        int i = tid + k * 512;
        if (i < count) {
            int r = myrec[k];
            int p = atomicAdd(&cur[r >> 17], 1);
            colsh[p] = r & 0x1FFFF;
        }
    }
    __syncthreads();

    // ---- gather: wave w -> nodes node0 + w*8 .. +7 ----
    const int wid  = tid >> 6;
    const int lane = tid & 63;
    const int g    = lane >> 4;      // edge group 0..3
    const int c2   = lane & 15;      // half2 channel pair
    for (int i = 0; i < 8; ++i) {
        const int dloc = wid * 8 + i;
        const int n = node0 + dloc;
        if (n >= N) break;           // only the tail bucket; uniform per wave
        const float adst_n = adst[n];
        float l = 0.0f, accx = 0.0f, accy = 0.0f;
        if (g == 0) {                // self loop
            float p = __expf(leaky(asrc[n] + adst_n));
            float2 hv = __half22float2(h2[(size_t)n * 16 + c2]);
            l = p; accx = p * hv.x; accy = p * hv.y;
        }
        const int base = loff[dloc];
        const int nch  = lpad[dloc] >> 2;    // 4-edge chunks
        for (int c = g; c < nch; c += 4) {   // clamp-free (sentinel-padded x4)
            const int4_t cc = *(const int4_t*)(&colsh[base + c * 4]);
            const int s0 = cc[0], s1 = cc[1], s2 = cc[2], s3 = cc[3];
            float a0 = asrc[s0], a1 = asrc[s1], a2 = asrc[s2], a3 = asrc[s3];
            float2 h0 = __half22float2(h2[(size_t)s0 * 16 + c2]);
            float2 h1 = __half22float2(h2[(size_t)s1 * 16 + c2]);
            float2 hv2 = __half22float2(h2[(size_t)s2 * 16 + c2]);
            float2 h3 = __half22float2(h2[(size_t)s3 * 16 + c2]);
            float p0 = __expf(leaky(a0 + adst_n));
            float p1 = __expf(leaky(a1 + adst_n));
            float p2 = __expf(leaky(a2 + adst_n));
            float p3 = __expf(leaky(a3 + adst_n));
            l += (p0 + p1) + (p2 + p3);
            accx += p0 * h0.x + p1 * h1.x + p2 * hv2.x + p3 * h3.x;
            accy += p0 * h0.y + p1 * h1.y + p2 * hv2.y + p3 * h3.y;
        }
        l    += __shfl_xor(l, 16);    l    += __shfl_xor(l, 32);
        accx += __shfl_xor(accx, 16); accx += __shfl_xor(accx, 32);
        accy += __shfl_xor(accy, 16); accy += __shfl_xor(accy, 32);
        if (g == 0) {
            float inv = 1.0f / l;
            float2 bb = ((const float2*)bias)[c2];
            float2 o;
            o.x = fmaxf(accx * inv + bb.x, 0.0f);
            o.y = fmaxf(accy * inv + bb.y, 0.0f);
            ((float2*)out)[(size_t)n * 16 + c2] = o;
        }
    }
}

extern "C" void kernel_launch(void* const* d_in, const int* in_sizes, int n_in,
                              void* d_out, int out_size, void* d_ws, size_t ws_size,
                              hipStream_t stream) {
    const float* x        = (const float*)d_in[0];
    const int*   eidx     = (const int*)d_in[1];   // [2, E] flat int32
    const float* W        = (const float*)d_in[2];
    const float* att_src  = (const float*)d_in[3];
    const float* att_dst  = (const float*)d_in[4];
    const float* bias     = (const float*)d_in[5];
    float* out = (float*)d_out;

    const int N = in_sizes[0] / IN_F;
    const int E = in_sizes[1] / 2;
    const int* src = eidx;
    const int* dst = eidx + E;

    const int NB  = (N + BK - 1) >> BK_SHIFT;    // 1563 buckets
    const int epb = (E + NBLKA - 1) / NBLKA;     // edges per partition block

    // Workspace (4 B elems, ~23 MB)
    int* u = (int*)d_ws;
    size_t o = 0;
    __half2* h2     = (__half2*)(u + o); o += (size_t)(N + 1) * 16;   // +sentinel row
    float*   asrc   = (float*)(u + o);   o += N + 1;                  // +sentinel
    float*   adst   = (float*)(u + o);   o += N;
    int*     cursor = u + o;             o += NBMAX;
    int*     recs   = u + o;             o += (size_t)NBMAX << CAPSHIFT;

    const int PB = (N + 63) / 64;                // MFMA proj blocks (64 nodes/block)

    k_zero<<<1, 512, 0, stream>>>(cursor, h2, asrc, N);
    k_projbpart<<<PB + NBLKA, 256, 0, stream>>>(x, W, att_src, att_dst,
                                                h2, asrc, adst, src, dst,
                                                cursor, recs, N, NB, E, epb, PB);
    k_pg<<<NB, 512, 0, stream>>>(recs, cursor, asrc, adst, h2, bias, out, NB, E, N);
}

// Round 17
// 147.723 us; speedup vs baseline: 2.4987x; 1.0455x over previous
//
#include <hip/hip_runtime.h>
#include <hip/hip_fp16.h>
#include <math.h>

#define IN_F 64
#define OUT_F 32
#define NEG_SLOPE 0.2f

#define BK_SHIFT 6
#define BK 64            // nodes per bucket
#define NBMAX 2048       // max buckets (N <= 131072)
#define NBLKA 256        // partition-role blocks
#define CAPSHIFT 11
#define CAP 2048         // fixed recs capacity per bucket (mean 1024, sd 32)
#define PSTAGE 4         // 512 thr x 4 = 2048 = CAP
#define COLCAP 2304      // LDS col capacity (2048 + pad slack)

typedef _Float16 half8_t __attribute__((ext_vector_type(8)));
typedef float float4_t __attribute__((ext_vector_type(4)));
typedef int int4_t __attribute__((ext_vector_type(4)));

// SESSION FINDINGS:
//  - gfx950 LDS atomics ~4.2 cy per LANE-op. 1-2/edge max.
//  - gfx950 device atomics: ~240ns same-ADDRESS, ~96ns same-LINE (r12/r13);
//    scattered 4B stores pay 64B write-allocate (r14). Partition records via
//    LDS-cursored mostly-contiguous runs (r11 structure).
//  - Harness re-poisons the full workspace INSIDE the timed region:
//    fillBufferAligned ~45us/iter (268MB @ ~6TB/s), fixed tax. Do NOT call
//    hipMemsetAsync (extra ~5us); zero via tiny kernel.
//  - r15/r16: proj+bpart fused ~53us; partition tail ran at 1 block/CU x 4
//    waves (occ 16%) -> r17: 1024-thread blocks for 4x tail latency-hiding.
//  - k_pg gather had 16-lane-redundant exp -> r17: exp once/edge in place
//    phase into pcol LDS.

__device__ __forceinline__ float leaky(float v) {
    return (v > 0.0f) ? v : NEG_SLOPE * v;
}

// Inclusive block scan, 512 threads. wsum: >=8-int LDS scratch.
__device__ __forceinline__ int incScan512(int v, int tid, int* wsum) {
    const int lane = tid & 63, wid = tid >> 6;
    #pragma unroll
    for (int m = 1; m < 64; m <<= 1) {
        int u = __shfl_up(v, m);
        if (lane >= m) v += u;
    }
    if (lane == 63) wsum[wid] = v;
    __syncthreads();
    int add = 0;
    for (int k = 0; k < wid; ++k) add += wsum[k];
    __syncthreads();
    return v + add;
}

// Tiny init: zero bucket cursors + gather sentinel (h2 row N = 0,
// asrc[N] = -1e30 => p = 0).
__global__ __launch_bounds__(512) void k_zero(int* __restrict__ cursor,
                                              __half2* __restrict__ h2,
                                              float* __restrict__ asrc, int N) {
    const int tid = threadIdx.x;
    #pragma unroll
    for (int k = 0; k < NBMAX / 512; ++k) cursor[tid + k * 512] = 0;
    if (tid < 16) h2[(size_t)N * 16 + tid] = __floats2half2_rn(0.0f, 0.0f);
    if (tid == 16) asrc[N] = -1e30f;
}

// Fused projection + bucket partition, 1024-thread blocks.
// Blocks [0, PB): MFMA projection (16 waves x 16 nodes = 256 nodes/block).
// Blocks [PB, PB+NBLKA): two-pass LDS partition: count this block's edge
//   slice per bucket; reserve contiguous chunk per non-empty bucket via ONE
//   global atomicAdd(cursor[b], c) (rotation-staggered); place via LDS
//   cursors. 16 waves/block hide the atomic/edge-pass latency in the tail.
__global__ __launch_bounds__(1024) void k_projbpart(
        const float* __restrict__ x, const float* __restrict__ W,
        const float* __restrict__ att_src, const float* __restrict__ att_dst,
        __half2* __restrict__ h2, float* __restrict__ asrc, float* __restrict__ adst,
        const int* __restrict__ src, const int* __restrict__ dst,
        int* __restrict__ cursor, int* __restrict__ recs,
        int N, int NB, int E, int epb, int PB) {
    __shared__ int smem[2 * NBMAX];          // 16 KB (partition role only)
    const int tid = threadIdx.x;

    if (blockIdx.x >= PB) {
        // ---- partition role ----
        int* cnt  = smem;
        int* lcur = smem + NBMAX;
        const int blk = blockIdx.x - PB;
        for (int b = tid; b < NB; b += 1024) cnt[b] = 0;
        __syncthreads();
        const int e0 = blk * epb, e1 = min(E, e0 + epb);
        for (int e = e0 + tid; e < e1; e += 1024)
            atomicAdd(&cnt[dst[e] >> BK_SHIFT], 1);
        __syncthreads();
        const int off = (blk * 389) % NB;            // stagger same-address chains
        for (int i = tid; i < NB; i += 1024) {
            int b = i + off; if (b >= NB) b -= NB;
            const int c = cnt[b];
            if (c > 0) lcur[b] = (b << CAPSHIFT) + atomicAdd(&cursor[b], c);
        }
        __syncthreads();
        for (int e = e0 + tid; e < e1; e += 1024) {
            int s = src[e];
            int d = dst[e];
            int p = atomicAdd(&lcur[d >> BK_SHIFT], 1);   // LDS cursor
            recs[p] = ((d & (BK - 1)) << 17) | s;
        }
        return;
    }

    // ---- MFMA projection role (16 waves x 16 nodes) ----
    const int wv   = tid >> 6;               // wave 0..15
    const int lane = tid & 63;
    const int m    = lane & 15;              // node-in-16 (A) / channel-in-group (B, C/D)
    const int quad = lane >> 4;              // 0..3
    const int node0 = (blockIdx.x * 16 + wv) * 16;
    if (node0 >= N) return;

    const int kb = quad * 8;
    // B fragments (W is 64x32, row-major W[k*32+c]); built once, L2-hot.
    half8_t b00, b01, b10, b11;
    #pragma unroll
    for (int j = 0; j < 8; ++j) {
        b00[j] = (_Float16)W[(kb + j) * OUT_F + m];
        b01[j] = (_Float16)W[(32 + kb + j) * OUT_F + m];
        b10[j] = (_Float16)W[(kb + j) * OUT_F + 16 + m];
        b11[j] = (_Float16)W[(32 + kb + j) * OUT_F + 16 + m];
    }
    // A fragments: x row (clamped in the tail block), 2x float4 per K-chunk.
    const int row = min(node0 + m, N - 1);
    const float* xr = x + (size_t)row * IN_F + kb;
    float4_t xa = *(const float4_t*)(xr);
    float4_t xb = *(const float4_t*)(xr + 4);
    float4_t xc = *(const float4_t*)(xr + 32);
    float4_t xd = *(const float4_t*)(xr + 36);
    half8_t a0, a1;
    #pragma unroll
    for (int j = 0; j < 4; ++j) {
        a0[j] = (_Float16)xa[j]; a0[4 + j] = (_Float16)xb[j];
        a1[j] = (_Float16)xc[j]; a1[4 + j] = (_Float16)xd[j];
    }
    float4_t acc0 = {0.f, 0.f, 0.f, 0.f};
    float4_t acc1 = {0.f, 0.f, 0.f, 0.f};
    acc0 = __builtin_amdgcn_mfma_f32_16x16x32_f16(a0, b00, acc0, 0, 0, 0);
    acc0 = __builtin_amdgcn_mfma_f32_16x16x32_f16(a1, b01, acc0, 0, 0, 0);
    acc1 = __builtin_amdgcn_mfma_f32_16x16x32_f16(a0, b10, acc1, 0, 0, 0);
    acc1 = __builtin_amdgcn_mfma_f32_16x16x32_f16(a1, b11, acc1, 0, 0, 0);

    // Epilogue: h2 (fp16 pairs) + asrc/adst per node.
    const float aS0 = att_src[m], aS1 = att_src[16 + m];
    const float aD0 = att_dst[m], aD1 = att_dst[16 + m];
    #pragma unroll
    for (int r = 0; r < 4; ++r) {
        const int node = node0 + quad * 4 + r;
        float h0 = acc0[r], h1 = acc1[r];
        float h0p = __shfl_xor(h0, 1);
        float h1p = __shfl_xor(h1, 1);
        if (node < N && (m & 1) == 0) {
            __half2 hv;
            hv.x = __float2half_rn(h0); hv.y = __float2half_rn(h0p);
            h2[(size_t)node * 16 + (m >> 1)] = hv;
            __half2 hw;
            hw.x = __float2half_rn(h1); hw.y = __float2half_rn(h1p);
            h2[(size_t)node * 16 + 8 + (m >> 1)] = hw;
        }
        float vs = h0 * aS0 + h1 * aS1;
        float vd = h0 * aD0 + h1 * aD1;
        #pragma unroll
        for (int mm = 1; mm < 16; mm <<= 1) {
            vs += __shfl_xor(vs, mm);
            vd += __shfl_xor(vd, mm);
        }
        if (node < N && m == 0) {
            asrc[node] = vs;
            adst[node] = vd;
        }
    }
}

// Fused place+gather: one block per bucket (64 nodes, 512 threads = 8 waves).
// Phase 1 (place): fine histogram; padded (x4) scan; place (col, p) into
// sentinel-prefilled LDS — p = exp(leaky(asrc[s]+adst[d])) computed ONCE per
// edge here (sentinel slots keep p=0). Phase 2 (gather): wave w handles nodes
// w*8..w*8+7; 4x16-lane groups read (col,p) chunks from LDS and do pure
// p*h FMAs with broadcast h2 loads.
__global__ __launch_bounds__(512) void k_pg(const int* __restrict__ recs,
                                            const int* __restrict__ cursor,
                                            const float* __restrict__ asrc,
                                            const float* __restrict__ adst,
                                            const __half2* __restrict__ h2,
                                            const float* __restrict__ bias,
                                            float* __restrict__ out,
                                            int NB, int E, int N) {
    __shared__ __align__(16) int colsh[COLCAP];
    __shared__ __align__(16) float pcol[COLCAP];
    __shared__ int fineCnt[BK];
    __shared__ int cur[BK];
    __shared__ int loff[BK];
    __shared__ int lpad[BK];
    __shared__ float adl[BK];
    __shared__ int wsum[8];
    const int b = blockIdx.x, tid = threadIdx.x;
    const int node0 = b << BK_SHIFT;

    const size_t cb0 = (size_t)b << CAPSHIFT;
    const int count = min(cursor[b], CAP);

    // ---- init: sentinel prefill + zero counts + stage adst ----
    for (int i = tid; i < COLCAP; i += 512) { colsh[i] = N; pcol[i] = 0.0f; }
    if (tid < BK) {
        fineCnt[tid] = 0;
        const int n = node0 + tid;
        adl[tid] = (n < N) ? adst[n] : 0.0f;
    }
    __syncthreads();

    // ---- fine histogram (register-staged) ----
    int myrec[PSTAGE];
    #pragma unroll
    for (int k = 0; k < PSTAGE; ++k) {
        int i = tid + k * 512;
        if (i < count) {
            int v = recs[cb0 + i];
            myrec[k] = v;
            atomicAdd(&fineCnt[v >> 17], 1);
        }
    }
    __syncthreads();

    // ---- padded (x4) scan of per-node counts ----
    const int v0 = (tid < BK) ? fineCnt[tid] : 0;
    const int pv = (v0 + 3) & ~3;
    const int vin = (tid < BK) ? pv : 0;
    const int pinc = incScan512(vin, tid, wsum);
    const int pexcl = pinc - vin;
    if (tid < BK) {
        loff[tid] = pexcl;       // multiple of 4 -> 16B-aligned chunks
        lpad[tid] = pv;
        cur[tid]  = pexcl;
    }
    __syncthreads();

    // ---- place into LDS (col, p): exp computed once per edge ----
    #pragma unroll
    for (int k = 0; k < PSTAGE; ++k) {
        int i = tid + k * 512;
        if (i < count) {
            int r = myrec[k];
            int d = r >> 17;
            int s = r & 0x1FFFF;
            int p = atomicAdd(&cur[d], 1);
            colsh[p] = s;
            pcol[p] = __expf(leaky(asrc[s] + adl[d]));
        }
    }
    __syncthreads();

    // ---- gather: wave w -> nodes node0 + w*8 .. +7 ----
    const int wid  = tid >> 6;
    const int lane = tid & 63;
    const int g    = lane >> 4;      // edge group 0..3
    const int c2   = lane & 15;      // half2 channel pair
    for (int i = 0; i < 8; ++i) {
        const int dloc = wid * 8 + i;
        const int n = node0 + dloc;
        if (n >= N) break;           // only the tail bucket; uniform per wave
        float l = 0.0f, accx = 0.0f, accy = 0.0f;
        if (g == 0) {                // self loop
            float p = __expf(leaky(asrc[n] + adl[dloc]));
            float2 hv = __half22float2(h2[(size_t)n * 16 + c2]);
            l = p; accx = p * hv.x; accy = p * hv.y;
        }
        const int base = loff[dloc];
        const int nch  = lpad[dloc] >> 2;    // 4-edge chunks
        for (int c = g; c < nch; c += 4) {   // clamp-free (sentinel-padded x4)
            const int4_t cc = *(const int4_t*)(&colsh[base + c * 4]);
            const float4_t pp = *(const float4_t*)(&pcol[base + c * 4]);
            const int s0 = cc[0], s1 = cc[1], s2 = cc[2], s3 = cc[3];
            float2 h0 = __half22float2(h2[(size_t)s0 * 16 + c2]);
            float2 h1 = __half22float2(h2[(size_t)s1 * 16 + c2]);
            float2 hv2 = __half22float2(h2[(size_t)s2 * 16 + c2]);
            float2 h3 = __half22float2(h2[(size_t)s3 * 16 + c2]);
            l += (pp[0] + pp[1]) + (pp[2] + pp[3]);
            accx += pp[0] * h0.x + pp[1] * h1.x + pp[2] * hv2.x + pp[3] * h3.x;
            accy += pp[0] * h0.y + pp[1] * h1.y + pp[2] * hv2.y + pp[3] * h3.y;
        }
        l    += __shfl_xor(l, 16);    l    += __shfl_xor(l, 32);
        accx += __shfl_xor(accx, 16); accx += __shfl_xor(accx, 32);
        accy += __shfl_xor(accy, 16); accy += __shfl_xor(accy, 32);
        if (g == 0) {
            float inv = 1.0f / l;
            float2 bb = ((const float2*)bias)[c2];
            float2 o;
            o.x = fmaxf(accx * inv + bb.x, 0.0f);
            o.y = fmaxf(accy * inv + bb.y, 0.0f);
            ((float2*)out)[(size_t)n * 16 + c2] = o;
        }
    }
}

extern "C" void kernel_launch(void* const* d_in, const int* in_sizes, int n_in,
                              void* d_out, int out_size, void* d_ws, size_t ws_size,
                              hipStream_t stream) {
    const float* x        = (const float*)d_in[0];
    const int*   eidx     = (const int*)d_in[1];   // [2, E] flat int32
    const float* W        = (const float*)d_in[2];
    const float* att_src  = (const float*)d_in[3];
    const float* att_dst  = (const float*)d_in[4];
    const float* bias     = (const float*)d_in[5];
    float* out = (float*)d_out;

    const int N = in_sizes[0] / IN_F;
    const int E = in_sizes[1] / 2;
    const int* src = eidx;
    const int* dst = eidx + E;

    const int NB  = (N + BK - 1) >> BK_SHIFT;    // 1563 buckets
    const int epb = (E + NBLKA - 1) / NBLKA;     // edges per partition block

    // Workspace (4 B elems, ~23 MB)
    int* u = (int*)d_ws;
    size_t o = 0;
    __half2* h2     = (__half2*)(u + o); o += (size_t)(N + 1) * 16;   // +sentinel row
    float*   asrc   = (float*)(u + o);   o += N + 1;                  // +sentinel
    float*   adst   = (float*)(u + o);   o += N;
    int*     cursor = u + o;             o += NBMAX;
    int*     recs   = u + o;             o += (size_t)NBMAX << CAPSHIFT;

    const int PB = (N + 255) / 256;              // MFMA proj blocks (256 nodes/block)

    k_zero<<<1, 512, 0, stream>>>(cursor, h2, asrc, N);
    k_projbpart<<<PB + NBLKA, 1024, 0, stream>>>(x, W, att_src, att_dst,
                                                 h2, asrc, adst, src, dst,
                                                 cursor, recs, N, NB, E, epb, PB);
    k_pg<<<NB, 512, 0, stream>>>(recs, cursor, asrc, adst, h2, bias, out, NB, E, N);
}